// Round 1
// baseline (819.220 us; speedup 1.0000x reference)
//
#include <hip/hip_runtime.h>
#include <hip/hip_bf16.h>

#define N_NODES  2000
#define N_FEAT   128
#define LOOKBACK 128
#define TFEAT    36
#define FC1      256
#define OUTCOLS  (N_NODES * N_FEAT)   // 256000
#define DELTA_MIN 0.05f

// ---------------- Kernel 1: hidden layers (transposed store) ----------------
// hs[j*128 + t] = relu(layer_initial[t,:] . Ws1[:,j] + bs1[j])
// ht[j*128 + t] = relu(time_feats[t,:]    . Wt1[:,j] + bt1[j])
__global__ __launch_bounds__(256)
void k_hidden(const float* __restrict__ time_feats,
              const float* __restrict__ layer_initial,
              const float* __restrict__ Ws1, const float* __restrict__ bs1,
              const float* __restrict__ Wt1, const float* __restrict__ bt1,
              float* __restrict__ hs, float* __restrict__ ht) {
    const int t = blockIdx.x;    // 0..127
    const int j = threadIdx.x;   // 0..255
    const float* li = layer_initial + (size_t)t * N_NODES;
    float accs = bs1[j];
#pragma unroll 4
    for (int n = 0; n < N_NODES; ++n)
        accs = fmaf(li[n], Ws1[(size_t)n * FC1 + j], accs);
    const float* tf = time_feats + (size_t)t * TFEAT;
    float acct = bt1[j];
#pragma unroll
    for (int q = 0; q < TFEAT; ++q)
        acct = fmaf(tf[q], Wt1[(size_t)q * FC1 + j], acct);
    hs[j * LOOKBACK + t] = fmaxf(accs, 0.0f);
    ht[j * LOOKBACK + t] = fmaxf(acct, 0.0f);
}

// ---------------- Kernel 2: sliced embedding gather+GEMV --------------------
// One block per node n. Threads: t = tid&127, fsel = tid>>7 (wave-uniform).
// emb[t,n,f] = relu(hs_row . Ws2[:,c] + bs2[c]) + relu(ht_row . Wt2[:,c] + bt2[c])
// fsel==0 -> U1[n][t] ; fsel==1 -> U2T[t][n]
__global__ __launch_bounds__(256)
void k_emb(const float* __restrict__ Ws2, const float* __restrict__ bs2,
           const float* __restrict__ Wt2, const float* __restrict__ bt2,
           const float* __restrict__ hs, const float* __restrict__ ht,
           const int* __restrict__ idxp, const int* __restrict__ tdp,
           float* __restrict__ U1, float* __restrict__ U2T) {
    const int n    = blockIdx.x;
    const int tid  = threadIdx.x;
    const int t    = tid & 127;
    const int fsel = tid >> 7;
    const int idx = idxp[0], td = tdp[0];
    const int i1 = (td >= 0) ? (idx - td) : idx;
    const int i2 = (td >= 0) ? idx        : (idx + td);
    const int f  = fsel ? i2 : i1;
    const size_t c = (size_t)n * N_FEAT + f;

    const float* hsp = hs + t;   // hs[k*128 + t]
    const float* htp = ht + t;
    float accS = 0.0f, accT = 0.0f;
#pragma unroll 4
    for (int k = 0; k < FC1; ++k) {
        const float wS = Ws2[(size_t)k * OUTCOLS + c];   // wave-uniform (scalar) load
        const float wT = Wt2[(size_t)k * OUTCOLS + c];
        accS = fmaf(hsp[k * LOOKBACK], wS, accS);        // coalesced across t
        accT = fmaf(htp[k * LOOKBACK], wT, accT);
    }
    const float val = fmaxf(accS + bs2[c], 0.0f) + fmaxf(accT + bt2[c], 0.0f);
    if (fsel == 0) U1[n * LOOKBACK + t] = val;
    else           U2T[t * N_NODES + n] = val;
}

// ---------------- Kernel 3: V1 = U1 @ B  (2000 x 128) -----------------------
__global__ __launch_bounds__(128)
void k_v1(const float* __restrict__ U1, const float* __restrict__ B,
          float* __restrict__ V1) {
    const int n = blockIdx.x;
    const int s = threadIdx.x;   // 0..127
    const float* u = U1 + n * LOOKBACK;
    float acc = 0.0f;
#pragma unroll 4
    for (int t = 0; t < LOOKBACK; ++t)
        acc = fmaf(u[t], B[t * LOOKBACK + s], acc);
    V1[n * LOOKBACK + s] = acc;
}

// ---------------- Kernel 4: x = V1 @ U2T, threshold, softmax, write ---------
#define ROWS   8
#define KXT    256
#define MCHUNK 8    // ceil(2000/256)

__global__ __launch_bounds__(256)
void k_x(const float* __restrict__ V1, const float* __restrict__ U2T,
         float* __restrict__ out) {
    __shared__ float v1s[ROWS][LOOKBACK];
    __shared__ float sred[4][ROWS];

    const int r0  = blockIdx.x * ROWS;
    const int tid = threadIdx.x;

    for (int i = tid; i < ROWS * LOOKBACK; i += KXT)
        v1s[i >> 7][i & 127] = V1[(r0 + (i >> 7)) * LOOKBACK + (i & 127)];
    __syncthreads();

    float acc[ROWS][MCHUNK];
#pragma unroll
    for (int r = 0; r < ROWS; ++r)
#pragma unroll
        for (int cc = 0; cc < MCHUNK; ++cc) acc[r][cc] = 0.0f;

    for (int s = 0; s < LOOKBACK; ++s) {
        float u[MCHUNK];
#pragma unroll
        for (int cc = 0; cc < MCHUNK; ++cc) {
            const int m = cc * KXT + tid;
            u[cc] = (m < N_NODES) ? U2T[s * N_NODES + m] : 0.0f;
        }
#pragma unroll
        for (int r = 0; r < ROWS; ++r) {
            const float v = v1s[r][s];
#pragma unroll
            for (int cc = 0; cc < MCHUNK; ++cc)
                acc[r][cc] = fmaf(v, u[cc], acc[r][cc]);
        }
    }

    // threshold in place
#pragma unroll
    for (int r = 0; r < ROWS; ++r)
#pragma unroll
        for (int cc = 0; cc < MCHUNK; ++cc)
            acc[r][cc] = (acc[r][cc] >= DELTA_MIN) ? acc[r][cc] : 0.0f;

    const int wave = tid >> 6;
    const int lane = tid & 63;

    // row max (block-wide)
    float rmax[ROWS];
#pragma unroll
    for (int r = 0; r < ROWS; ++r) {
        float lm = -1e30f;
#pragma unroll
        for (int cc = 0; cc < MCHUNK; ++cc)
            if (cc * KXT + tid < N_NODES) lm = fmaxf(lm, acc[r][cc]);
        for (int off = 32; off >= 1; off >>= 1)
            lm = fmaxf(lm, __shfl_xor(lm, off, 64));
        rmax[r] = lm;
    }
    if (lane == 0)
#pragma unroll
        for (int r = 0; r < ROWS; ++r) sred[wave][r] = rmax[r];
    __syncthreads();
#pragma unroll
    for (int r = 0; r < ROWS; ++r)
        rmax[r] = fmaxf(fmaxf(sred[0][r], sred[1][r]), fmaxf(sred[2][r], sred[3][r]));
    __syncthreads();

    // exp + row sum
    float rsum[ROWS];
#pragma unroll
    for (int r = 0; r < ROWS; ++r) {
        float ls = 0.0f;
#pragma unroll
        for (int cc = 0; cc < MCHUNK; ++cc) {
            const int m = cc * KXT + tid;
            if (m < N_NODES) {
                acc[r][cc] = __expf(acc[r][cc] - rmax[r]);
                ls += acc[r][cc];
            }
        }
        for (int off = 32; off >= 1; off >>= 1)
            ls += __shfl_xor(ls, off, 64);
        rsum[r] = ls;
    }
    if (lane == 0)
#pragma unroll
        for (int r = 0; r < ROWS; ++r) sred[wave][r] = rsum[r];
    __syncthreads();
#pragma unroll
    for (int r = 0; r < ROWS; ++r) {
        const float inv = 1.0f / (sred[0][r] + sred[1][r] + sred[2][r] + sred[3][r]);
#pragma unroll
        for (int cc = 0; cc < MCHUNK; ++cc) {
            const int m = cc * KXT + tid;
            if (m < N_NODES)
                out[(size_t)(r0 + r) * N_NODES + m] = acc[r][cc] * inv;
        }
    }
}

// ---------------- launch ----------------------------------------------------
extern "C" void kernel_launch(void* const* d_in, const int* in_sizes, int n_in,
                              void* d_out, int out_size, void* d_ws, size_t ws_size,
                              hipStream_t stream) {
    const float* time_feats    = (const float*)d_in[0];
    const float* layer_initial = (const float*)d_in[1];
    const float* Ws1           = (const float*)d_in[2];
    const float* bs1           = (const float*)d_in[3];
    const float* Ws2           = (const float*)d_in[4];
    const float* bs2           = (const float*)d_in[5];
    const float* Wt1           = (const float*)d_in[6];
    const float* bt1           = (const float*)d_in[7];
    const float* Wt2           = (const float*)d_in[8];
    const float* bt2           = (const float*)d_in[9];
    const float* B             = (const float*)d_in[10];
    const int*   idxp          = (const int*)d_in[11];
    const int*   tdp           = (const int*)d_in[12];
    float* out = (float*)d_out;

    float* ws = (float*)d_ws;
    float* hs  = ws;                         // 256*128
    float* ht  = hs  + FC1 * LOOKBACK;       // 256*128
    float* U1  = ht  + FC1 * LOOKBACK;       // 2000*128
    float* U2T = U1  + N_NODES * LOOKBACK;   // 128*2000
    float* V1  = U2T + LOOKBACK * N_NODES;   // 2000*128

    hipLaunchKernelGGL(k_hidden, dim3(LOOKBACK), dim3(256), 0, stream,
                       time_feats, layer_initial, Ws1, bs1, Wt1, bt1, hs, ht);
    hipLaunchKernelGGL(k_emb, dim3(N_NODES), dim3(256), 0, stream,
                       Ws2, bs2, Wt2, bt2, hs, ht, idxp, tdp, U1, U2T);
    hipLaunchKernelGGL(k_v1, dim3(N_NODES), dim3(128), 0, stream,
                       U1, B, V1);
    hipLaunchKernelGGL(k_x, dim3(N_NODES / ROWS), dim3(KXT), 0, stream,
                       V1, U2T, out);
}

// Round 2
// 643.837 us; speedup vs baseline: 1.2724x; 1.2724x over previous
//
#include <hip/hip_runtime.h>
#include <hip/hip_bf16.h>

#define N_NODES  2000
#define N_FEAT   128
#define LOOKBACK 128
#define TFEAT    36
#define FC1      256
#define OUTCOLS  (N_NODES * N_FEAT)   // 256000
#define DELTA_MIN 0.05f
#define KSPLIT   16
#define KCHUNK   (N_NODES / KSPLIT)   // 125

// ---- K1: spatial hidden layer, split-K partials -----------------------------
// grid = KSPLIT*128 blocks (s = b>>7, t = b&127), 256 threads (j).
// partial[(s*128+t)*256 + j] = sum_{k in chunk s} li[t,k] * Ws1[k,j]
__global__ __launch_bounds__(256)
void k_hidden_partial(const float* __restrict__ layer_initial,
                      const float* __restrict__ Ws1,
                      float* __restrict__ partial) {
    const int s = blockIdx.x >> 7;
    const int t = blockIdx.x & 127;
    const int j = threadIdx.x;
    const float* li = layer_initial + (size_t)t * N_NODES + s * KCHUNK;
    const float* w  = Ws1 + (size_t)s * KCHUNK * FC1 + j;
    float acc = 0.0f;
#pragma unroll 5
    for (int k = 0; k < KCHUNK; ++k)
        acc = fmaf(li[k], w[(size_t)k * FC1], acc);
    partial[(size_t)blockIdx.x * FC1 + j] = acc;   // coalesced
}

// ---- K2: reduce partials + bias + relu (transposed store), temporal layer ---
// hs[j*128+t], ht[j*128+t]
__global__ __launch_bounds__(256)
void k_hidden_finish(const float* __restrict__ partial,
                     const float* __restrict__ bs1,
                     const float* __restrict__ time_feats,
                     const float* __restrict__ Wt1,
                     const float* __restrict__ bt1,
                     float* __restrict__ hs, float* __restrict__ ht) {
    const int t = blockIdx.x;    // 0..127
    const int j = threadIdx.x;   // 0..255
    float acc = bs1[j];
#pragma unroll
    for (int s = 0; s < KSPLIT; ++s)
        acc += partial[((size_t)s * LOOKBACK + t) * FC1 + j];
    hs[j * LOOKBACK + t] = fmaxf(acc, 0.0f);

    const float* tf = time_feats + t * TFEAT;
    float acct = bt1[j];
#pragma unroll
    for (int q = 0; q < TFEAT; ++q)
        acct = fmaf(tf[q], Wt1[q * FC1 + j], acct);
    ht[j * LOOKBACK + t] = fmaxf(acct, 0.0f);
}

// ---- K3: DRAM-friendly gather of the 2 needed feature columns --------------
// Wg[m][k][n], m: 0=Ws2/f1 1=Ws2/f2 2=Wt2/f1 3=Wt2/f2.  Bg[m][n] biases.
// grid = 256k * 8 chunks; lanes walk consecutive nodes (512B stride -> the
// block touches one contiguous ~125KB region: streaming-friendly).
__global__ __launch_bounds__(256)
void k_gather(const float* __restrict__ Ws2, const float* __restrict__ bs2,
              const float* __restrict__ Wt2, const float* __restrict__ bt2,
              const int* __restrict__ idxp, const int* __restrict__ tdp,
              float* __restrict__ Wg, float* __restrict__ Bg) {
    const int k  = blockIdx.x >> 3;
    const int nc = blockIdx.x & 7;
    const int n  = nc * 250 + threadIdx.x;
    if (threadIdx.x >= 250) return;
    const int idx = idxp[0], td = tdp[0];
    const int i1 = (td >= 0) ? (idx - td) : idx;
    const int i2 = (td >= 0) ? idx        : (idx + td);
    const size_t base = (size_t)k * OUTCOLS + (size_t)n * N_FEAT;
    Wg[((size_t)0 * FC1 + k) * N_NODES + n] = Ws2[base + i1];
    Wg[((size_t)1 * FC1 + k) * N_NODES + n] = Ws2[base + i2];
    Wg[((size_t)2 * FC1 + k) * N_NODES + n] = Wt2[base + i1];
    Wg[((size_t)3 * FC1 + k) * N_NODES + n] = Wt2[base + i2];
    if (k == 0) {
        const size_t nb = (size_t)n * N_FEAT;
        Bg[0 * N_NODES + n] = bs2[nb + i1];
        Bg[1 * N_NODES + n] = bs2[nb + i2];
        Bg[2 * N_NODES + n] = bt2[nb + i1];
        Bg[3 * N_NODES + n] = bt2[nb + i2];
    }
}

// ---- K4: emb slice GEMV from compact Wg, fused V1 = U1row @ B --------------
// block = node n; threads: t = tid&127, fsel = tid>>7.
__global__ __launch_bounds__(256)
void k_emb2(const float* __restrict__ Wg, const float* __restrict__ Bg,
            const float* __restrict__ hs, const float* __restrict__ ht,
            const float* __restrict__ B,
            float* __restrict__ U2T, float* __restrict__ V1) {
    __shared__ float u1row[LOOKBACK];
    const int n    = blockIdx.x;
    const int tid  = threadIdx.x;
    const int t    = tid & 127;
    const int fsel = tid >> 7;

    const float* wS  = Wg + ((size_t)(0 + fsel) * FC1) * N_NODES + n;
    const float* wT  = Wg + ((size_t)(2 + fsel) * FC1) * N_NODES + n;
    const float* hsp = hs + t;
    const float* htp = ht + t;
    float accS = 0.0f, accT = 0.0f;
#pragma unroll 8
    for (int k = 0; k < FC1; ++k) {
        accS = fmaf(hsp[k * LOOKBACK], wS[(size_t)k * N_NODES], accS);
        accT = fmaf(htp[k * LOOKBACK], wT[(size_t)k * N_NODES], accT);
    }
    const float val = fmaxf(accS + Bg[fsel * N_NODES + n], 0.0f)
                    + fmaxf(accT + Bg[(2 + fsel) * N_NODES + n], 0.0f);
    if (fsel == 0) u1row[t] = val;
    else           U2T[(size_t)t * N_NODES + n] = val;
    __syncthreads();

    if (tid < LOOKBACK) {   // V1[n,s] = sum_t u1row[t] * B[t,s]
        const int s = tid;
        float acc = 0.0f;
#pragma unroll 8
        for (int tt = 0; tt < LOOKBACK; ++tt)
            acc = fmaf(u1row[tt], B[tt * LOOKBACK + s], acc);
        V1[(size_t)n * LOOKBACK + s] = acc;
    }
}

// ---- K5: x = V1 @ U2T, threshold, row softmax, write ------------------------
#define ROWS   8
#define KXT    256
#define MCHUNK 8

__global__ __launch_bounds__(256)
void k_x(const float* __restrict__ V1, const float* __restrict__ U2T,
         float* __restrict__ out) {
    __shared__ float v1s[ROWS][LOOKBACK];
    __shared__ float sred[4][ROWS];

    const int r0  = blockIdx.x * ROWS;
    const int tid = threadIdx.x;

    for (int i = tid; i < ROWS * LOOKBACK; i += KXT)
        v1s[i >> 7][i & 127] = V1[(r0 + (i >> 7)) * LOOKBACK + (i & 127)];
    __syncthreads();

    float acc[ROWS][MCHUNK];
#pragma unroll
    for (int r = 0; r < ROWS; ++r)
#pragma unroll
        for (int cc = 0; cc < MCHUNK; ++cc) acc[r][cc] = 0.0f;

    for (int s = 0; s < LOOKBACK; ++s) {
        float u[MCHUNK];
#pragma unroll
        for (int cc = 0; cc < MCHUNK; ++cc) {
            const int m = cc * KXT + tid;
            u[cc] = (m < N_NODES) ? U2T[s * N_NODES + m] : 0.0f;
        }
#pragma unroll
        for (int r = 0; r < ROWS; ++r) {
            const float v = v1s[r][s];
#pragma unroll
            for (int cc = 0; cc < MCHUNK; ++cc)
                acc[r][cc] = fmaf(v, u[cc], acc[r][cc]);
        }
    }

#pragma unroll
    for (int r = 0; r < ROWS; ++r)
#pragma unroll
        for (int cc = 0; cc < MCHUNK; ++cc)
            acc[r][cc] = (acc[r][cc] >= DELTA_MIN) ? acc[r][cc] : 0.0f;

    const int wave = tid >> 6;
    const int lane = tid & 63;

    float rmax[ROWS];
#pragma unroll
    for (int r = 0; r < ROWS; ++r) {
        float lm = -1e30f;
#pragma unroll
        for (int cc = 0; cc < MCHUNK; ++cc)
            if (cc * KXT + tid < N_NODES) lm = fmaxf(lm, acc[r][cc]);
        for (int off = 32; off >= 1; off >>= 1)
            lm = fmaxf(lm, __shfl_xor(lm, off, 64));
        rmax[r] = lm;
    }
    if (lane == 0)
#pragma unroll
        for (int r = 0; r < ROWS; ++r) sred[wave][r] = rmax[r];
    __syncthreads();
#pragma unroll
    for (int r = 0; r < ROWS; ++r)
        rmax[r] = fmaxf(fmaxf(sred[0][r], sred[1][r]), fmaxf(sred[2][r], sred[3][r]));
    __syncthreads();

    float rsum[ROWS];
#pragma unroll
    for (int r = 0; r < ROWS; ++r) {
        float ls = 0.0f;
#pragma unroll
        for (int cc = 0; cc < MCHUNK; ++cc) {
            const int m = cc * KXT + tid;
            if (m < N_NODES) {
                acc[r][cc] = __expf(acc[r][cc] - rmax[r]);
                ls += acc[r][cc];
            }
        }
        for (int off = 32; off >= 1; off >>= 1)
            ls += __shfl_xor(ls, off, 64);
        rsum[r] = ls;
    }
    if (lane == 0)
#pragma unroll
        for (int r = 0; r < ROWS; ++r) sred[wave][r] = rsum[r];
    __syncthreads();
#pragma unroll
    for (int r = 0; r < ROWS; ++r) {
        const float inv = 1.0f / (sred[0][r] + sred[1][r] + sred[2][r] + sred[3][r]);
#pragma unroll
        for (int cc = 0; cc < MCHUNK; ++cc) {
            const int m = cc * KXT + tid;
            if (m < N_NODES)
                out[(size_t)(r0 + r) * N_NODES + m] = acc[r][cc] * inv;
        }
    }
}

// ---- launch -----------------------------------------------------------------
extern "C" void kernel_launch(void* const* d_in, const int* in_sizes, int n_in,
                              void* d_out, int out_size, void* d_ws, size_t ws_size,
                              hipStream_t stream) {
    const float* time_feats    = (const float*)d_in[0];
    const float* layer_initial = (const float*)d_in[1];
    const float* Ws1           = (const float*)d_in[2];
    const float* bs1           = (const float*)d_in[3];
    const float* Ws2           = (const float*)d_in[4];
    const float* bs2           = (const float*)d_in[5];
    const float* Wt1           = (const float*)d_in[6];
    const float* bt1           = (const float*)d_in[7];
    const float* Wt2           = (const float*)d_in[8];
    const float* bt2           = (const float*)d_in[9];
    const float* B             = (const float*)d_in[10];
    const int*   idxp          = (const int*)d_in[11];
    const int*   tdp           = (const int*)d_in[12];
    float* out = (float*)d_out;

    float* ws      = (float*)d_ws;
    float* partial = ws;                               // 16*128*256   = 524288
    float* hs      = partial + KSPLIT * LOOKBACK * FC1;// 256*128      = 32768
    float* ht      = hs + FC1 * LOOKBACK;              // 256*128      = 32768
    float* Wg      = ht + FC1 * LOOKBACK;              // 4*256*2000   = 2048000
    float* Bg      = Wg + 4 * FC1 * N_NODES;           // 4*2000       = 8000
    float* U2T     = Bg + 4 * N_NODES;                 // 128*2000     = 256000
    float* V1      = U2T + LOOKBACK * N_NODES;         // 2000*128     = 256000

    hipLaunchKernelGGL(k_hidden_partial, dim3(KSPLIT * LOOKBACK), dim3(256), 0, stream,
                       layer_initial, Ws1, partial);
    hipLaunchKernelGGL(k_hidden_finish, dim3(LOOKBACK), dim3(256), 0, stream,
                       partial, bs1, time_feats, Wt1, bt1, hs, ht);
    hipLaunchKernelGGL(k_gather, dim3(FC1 * 8), dim3(256), 0, stream,
                       Ws2, bs2, Wt2, bt2, idxp, tdp, Wg, Bg);
    hipLaunchKernelGGL(k_emb2, dim3(N_NODES), dim3(256), 0, stream,
                       Wg, Bg, hs, ht, B, U2T, V1);
    hipLaunchKernelGGL(k_x, dim3(N_NODES / ROWS), dim3(KXT), 0, stream,
                       V1, U2T, out);
}